// Round 13
// baseline (239.844 us; speedup 1.0000x reference)
//
#include <hip/hip_runtime.h>

#define N_NODES 50000
#define N_EDGES 800000
#define NFEAT   128
#define NHID    256
#define NCLASS  64

#define NPASS 8
#define PASS_W ((N_NODES + NPASS - 1) / NPASS)   // 6250 nodes per dst-range pass
#define ELLCAP 64

#define NPAIR   (N_EDGES / 2)                    // 400000 edge pairs
#define ECHUNK2 ((NPAIR + 255) / 256)            // 1563 pair chunks
#define FILL_B  (ECHUNK2 * NPASS)                // 12504
#define CVTX_B  ((N_NODES * 32 + 255) / 256)     // 6250
#define CVTW_B  (((65536 + 32768) + 255) / 256)  // 384

typedef unsigned short u16;
typedef unsigned int   u32;
typedef __attribute__((ext_vector_type(8))) u16   u16x8;
typedef __attribute__((ext_vector_type(8))) short s16x8;
typedef __attribute__((ext_vector_type(4))) float f32x4;

__device__ inline u16 f2bf(float f) {
    u32 u = __float_as_uint(f);
    u32 r = (u + 0x7FFFu + ((u >> 16) & 1u)) >> 16;   // RNE
    return (u16)r;
}
__device__ inline float bflo(u32 v) { return __uint_as_float(v << 16); }
__device__ inline float bfhi(u32 v) { return __uint_as_float(v & 0xFFFF0000u); }

// async global->LDS, 16B per lane; LDS dest must be wave-uniform base + lane*16
#define GLOAD_LDS16(g, l)                                                        \
    __builtin_amdgcn_global_load_lds(                                            \
        (const __attribute__((address_space(1))) u32*)(const void*)(g),          \
        (__attribute__((address_space(3))) u32*)(void*)(l), 16, 0, 0)

// ---------------- fused prep: ELL fill (XCD-binned, 2 edges/thread) | cvt_x | cvt_w ----------------
__global__ __launch_bounds__(256) void prep_fill_kernel(const float* __restrict__ x,
                                                        const int* __restrict__ ei,
                                                        const float* __restrict__ W1r,
                                                        const float* __restrict__ W1n,
                                                        const float* __restrict__ W2n,
                                                        const float* __restrict__ W2r,
                                                        u16* __restrict__ xa,
                                                        int* __restrict__ cnt,
                                                        int* __restrict__ ell,
                                                        u16* __restrict__ W1t,
                                                        u16* __restrict__ W2t) {
    int b = blockIdx.x;
    if (b < FILL_B) {
        // blockIdx&7 == XCD under round-robin mapping (fill blocks grid-contiguous from 0)
        int p = b & (NPASS - 1);
        int i = (b >> 3) * 256 + threadIdx.x;     // pair index
        if (i >= NPAIR) return;
        int2 d2 = reinterpret_cast<const int2*>(ei + N_EDGES)[i];
        u32 lo = (u32)(p * PASS_W);
        bool in0 = ((u32)d2.x - lo) < (u32)PASS_W;
        bool in1 = ((u32)d2.y - lo) < (u32)PASS_W;
        if (in0 | in1) {
            int2 s2 = reinterpret_cast<const int2*>(ei)[i];
            if (in0) {
                int pos = atomicAdd(&cnt[d2.x], 1);
                if (pos < ELLCAP) ell[(size_t)d2.x * ELLCAP + pos] = s2.x;
            }
            if (in1) {
                int pos = atomicAdd(&cnt[d2.y], 1);
                if (pos < ELLCAP) ell[(size_t)d2.y * ELLCAP + pos] = s2.y;
            }
        }
    } else if (b < FILL_B + CVTX_B) {
        int idx = (b - FILL_B) * 256 + threadIdx.x;
        if (idx >= N_NODES * 32) return;
        int r  = idx >> 5;
        int c4 = (idx & 31) * 4;
        float4 v = *reinterpret_cast<const float4*>(x + (size_t)r * NFEAT + c4);
        uint2 o;
        o.x = (u32)f2bf(v.x) | ((u32)f2bf(v.y) << 16);
        o.y = (u32)f2bf(v.z) | ((u32)f2bf(v.w) << 16);
        *reinterpret_cast<uint2*>(xa + (size_t)r * 256 + c4) = o;   // cols 0..127 of combined row
    } else {
        int id = (b - FILL_B - CVTX_B) * 256 + threadIdx.x;
        if (id < 65536) {
            int k = id & 255, n = id >> 8;
            float v = (k < NFEAT) ? W1r[(size_t)k * NHID + n]
                                  : W1n[(size_t)(k - NFEAT) * NHID + n];
            W1t[(size_t)n * 256 + k] = f2bf(v);
        } else if (id < 65536 + 32768) {
            int j = id - 65536;
            int k = j & 255, n = j >> 8;
            float v = (n < NCLASS) ? W2n[(size_t)k * NCLASS + n]
                                   : W2r[(size_t)k * NCLASS + (n - NCLASS)];
            W2t[(size_t)n * 256 + k] = f2bf(v);
        }
    }
}

// ---------------- gather 1: xa[n][128:256] = mean of xa[s][0:128] ----------------
// one wave per node, lane = u32 feature pair; 16-deep neighbor unroll (4KB in flight).
__global__ __launch_bounds__(256) void gather1_kernel(const int* __restrict__ cnt,
                                                      const int* __restrict__ ell,
                                                      u16* __restrict__ xa) {
    int gtid = blockIdx.x * 256 + threadIdx.x;
    int node = gtid >> 6;
    if (node >= N_NODES) return;
    int lane = threadIdx.x & 63;
    const u32* xrow = reinterpret_cast<const u32*>(xa);   // row stride 128 u32
    const int* idx = ell + (size_t)node * ELLCAP;
    int deg = cnt[node];
    if (deg > ELLCAP) deg = ELLCAP;
    float ax = 0.0f, ay = 0.0f;
    int j = 0;
    for (; j + 16 <= deg; j += 16) {
        int s[16]; u32 v[16];
        #pragma unroll
        for (int q = 0; q < 16; ++q) s[q] = idx[j + q];
        #pragma unroll
        for (int q = 0; q < 16; ++q) v[q] = xrow[(size_t)s[q] * 128 + lane];
        #pragma unroll
        for (int q = 0; q < 16; ++q) { ax += bflo(v[q]); ay += bfhi(v[q]); }
    }
    for (; j + 8 <= deg; j += 8) {
        int s[8]; u32 v[8];
        #pragma unroll
        for (int q = 0; q < 8; ++q) s[q] = idx[j + q];
        #pragma unroll
        for (int q = 0; q < 8; ++q) v[q] = xrow[(size_t)s[q] * 128 + lane];
        #pragma unroll
        for (int q = 0; q < 8; ++q) { ax += bflo(v[q]); ay += bfhi(v[q]); }
    }
    for (; j < deg; ++j) {
        u32 v = xrow[(size_t)idx[j] * 128 + lane];
        ax += bflo(v);
        ay += bfhi(v);
    }
    float invd = 1.0f / fmaxf((float)deg, 1.0f);
    u32 packed = (u32)f2bf(ax * invd) | ((u32)f2bf(ay * invd) << 16);
    reinterpret_cast<u32*>(xa + (size_t)node * 256 + 128)[lane] = packed;
}

// ---------------- gather 2: out[n][:] += mean of t[s][:] ----------------
// 2 nodes per wave (t rows = 32 u32), lane&31 = u32 pair; 16-deep unroll.
__global__ __launch_bounds__(256) void gather2_kernel(const int* __restrict__ cnt,
                                                      const int* __restrict__ ell,
                                                      const u16* __restrict__ t,
                                                      float* __restrict__ out) {
    int gtid = blockIdx.x * 256 + threadIdx.x;
    int wave = gtid >> 6;
    int lane = threadIdx.x & 63;
    int node = wave * 2 + (lane >> 5);
    int l    = lane & 31;
    if (node >= N_NODES) return;
    const u32* trow = reinterpret_cast<const u32*>(t);    // row stride 32 u32
    const int* idx = ell + (size_t)node * ELLCAP;
    int deg = cnt[node];
    if (deg > ELLCAP) deg = ELLCAP;
    float ax = 0.0f, ay = 0.0f;
    int j = 0;
    for (; j + 16 <= deg; j += 16) {
        int s[16]; u32 v[16];
        #pragma unroll
        for (int q = 0; q < 16; ++q) s[q] = idx[j + q];
        #pragma unroll
        for (int q = 0; q < 16; ++q) v[q] = trow[(size_t)s[q] * 32 + l];
        #pragma unroll
        for (int q = 0; q < 16; ++q) { ax += bflo(v[q]); ay += bfhi(v[q]); }
    }
    for (; j + 8 <= deg; j += 8) {
        int s[8]; u32 v[8];
        #pragma unroll
        for (int q = 0; q < 8; ++q) s[q] = idx[j + q];
        #pragma unroll
        for (int q = 0; q < 8; ++q) v[q] = trow[(size_t)s[q] * 32 + l];
        #pragma unroll
        for (int q = 0; q < 8; ++q) { ax += bflo(v[q]); ay += bfhi(v[q]); }
    }
    for (; j < deg; ++j) {
        u32 v = trow[(size_t)idx[j] * 32 + l];
        ax += bflo(v); ay += bfhi(v);
    }
    float invd = 1.0f / fmaxf((float)deg, 1.0f);
    float* o = out + (size_t)node * NCLASS + l * 2;
    o[0] += ax * invd;
    o[1] += ay * invd;
}

// ---------------- MFMA GEMM 1: h = relu(xa @ W1t^T + b1), bf16 out ----------------
// BN=256: one block per 128-row stripe covers all output cols (A staged once).
// 4 waves in 2x2 layout: each computes 64 rows x 128 cols (acc[4][8]).
__global__ __launch_bounds__(256) void gemm1_mfma(const u16* __restrict__ xa,
                                                  const u16* __restrict__ W1t,
                                                  const float* __restrict__ b1,
                                                  u16* __restrict__ h) {
    __shared__ u16 As[128 * 32];   // 8 KB
    __shared__ u16 Bs[256 * 32];   // 16 KB
    const int tid = threadIdx.x;
    const int r0 = blockIdx.x * 128;
    const int wid = tid >> 6, ln = tid & 63;
    const int wm = (wid & 1) * 64, wn = (wid >> 1) * 128;
    const int lr = ln & 15;
    const int lq = ln >> 4;

    f32x4 acc[4][8] = {};

    for (int k0 = 0; k0 < 256; k0 += 32) {
        #pragma unroll
        for (int it = 0; it < 2; ++it) {
            int c   = it * 256 + tid;      // A chunk 0..511
            int row = c >> 2;
            int ko  = (c & 3) * 8;
            GLOAD_LDS16(xa + (size_t)(r0 + row) * 256 + k0 + ko, As + c * 8);
        }
        #pragma unroll
        for (int it = 0; it < 4; ++it) {
            int c   = it * 256 + tid;      // B chunk 0..1023 (256 cols)
            int row = c >> 2;
            int ko  = (c & 3) * 8;
            GLOAD_LDS16(W1t + (size_t)row * 256 + k0 + ko, Bs + c * 8);
        }
        __syncthreads();

        s16x8 af[4], bf[8];
        #pragma unroll
        for (int i = 0; i < 4; ++i)
            af[i] = *reinterpret_cast<const s16x8*>(As + (wm + i * 16 + lr) * 32 + lq * 8);
        #pragma unroll
        for (int j = 0; j < 8; ++j)
            bf[j] = *reinterpret_cast<const s16x8*>(Bs + (wn + j * 16 + lr) * 32 + lq * 8);
        #pragma unroll
        for (int i = 0; i < 4; ++i)
            #pragma unroll
            for (int j = 0; j < 8; ++j)
                acc[i][j] = __builtin_amdgcn_mfma_f32_16x16x32_bf16(af[i], bf[j], acc[i][j], 0, 0, 0);
        __syncthreads();
    }

    #pragma unroll
    for (int i = 0; i < 4; ++i) {
        #pragma unroll
        for (int j = 0; j < 8; ++j) {
            int col = wn + j * 16 + lr;
            float bias = b1[col];
            #pragma unroll
            for (int r = 0; r < 4; ++r) {
                int row = r0 + wm + i * 16 + lq * 4 + r;
                if (row < N_NODES)
                    h[(size_t)row * 256 + col] = f2bf(fmaxf(acc[i][j][r] + bias, 0.0f));
            }
        }
    }
}

// ---------------- MFMA GEMM 2 (fused): cols 0..63 -> t (bf16), 64..127 -> out+b2 (f32) ----------------
__global__ __launch_bounds__(256) void gemm2_mfma(const u16* __restrict__ h,
                                                  const u16* __restrict__ W2t,
                                                  const float* __restrict__ b2,
                                                  u16* __restrict__ t,
                                                  float* __restrict__ out) {
    __shared__ u16 As[128 * 32];
    __shared__ u16 Bs[128 * 32];
    const int tid = threadIdx.x;
    const int r0 = blockIdx.x * 128;
    const int wid = tid >> 6, ln = tid & 63;
    const int wm = (wid & 1) * 64, wn = (wid >> 1) * 64;
    const int lr = ln & 15;
    const int lq = ln >> 4;

    f32x4 acc[4][4] = {};

    for (int k0 = 0; k0 < 256; k0 += 32) {
        #pragma unroll
        for (int it = 0; it < 2; ++it) {
            int c   = it * 256 + tid;
            int row = c >> 2;
            int ko  = (c & 3) * 8;
            GLOAD_LDS16(h   + (size_t)(r0 + row) * 256 + k0 + ko, As + c * 8);
            GLOAD_LDS16(W2t + (size_t)row * 256 + k0 + ko,        Bs + c * 8);
        }
        __syncthreads();

        s16x8 af[4], bf[4];
        #pragma unroll
        for (int i = 0; i < 4; ++i)
            af[i] = *reinterpret_cast<const s16x8*>(As + (wm + i * 16 + lr) * 32 + lq * 8);
        #pragma unroll
        for (int j = 0; j < 4; ++j)
            bf[j] = *reinterpret_cast<const s16x8*>(Bs + (wn + j * 16 + lr) * 32 + lq * 8);
        #pragma unroll
        for (int i = 0; i < 4; ++i)
            #pragma unroll
            for (int j = 0; j < 4; ++j)
                acc[i][j] = __builtin_amdgcn_mfma_f32_16x16x32_bf16(af[i], bf[j], acc[i][j], 0, 0, 0);
        __syncthreads();
    }

    #pragma unroll
    for (int i = 0; i < 4; ++i) {
        #pragma unroll
        for (int j = 0; j < 4; ++j) {
            int col = wn + j * 16 + lr;   // 0..127
            #pragma unroll
            for (int r = 0; r < 4; ++r) {
                int row = r0 + wm + i * 16 + lq * 4 + r;
                if (row >= N_NODES) continue;
                if (col < NCLASS) {
                    t[(size_t)row * NCLASS + col] = f2bf(acc[i][j][r]);
                } else {
                    int c = col - NCLASS;
                    out[(size_t)row * NCLASS + c] = acc[i][j][r] + b2[c];
                }
            }
        }
    }
}

extern "C" void kernel_launch(void* const* d_in, const int* in_sizes, int n_in,
                              void* d_out, int out_size, void* d_ws, size_t ws_size,
                              hipStream_t stream) {
    const float* x    = (const float*)d_in[0];
    const int*   ei   = (const int*)d_in[1];
    const float* W1n  = (const float*)d_in[2];
    const float* W1r  = (const float*)d_in[3];
    const float* b1   = (const float*)d_in[4];
    const float* W2n  = (const float*)d_in[5];
    const float* W2r  = (const float*)d_in[6];
    const float* b2   = (const float*)d_in[7];
    float* out = (float*)d_out;

    // workspace: cnt[50048] | ell[50000*64] | xa[50000*256] | h[50000*256] | t[50000*64] | W1t | W2t
    int* cnt = (int*)d_ws;
    int* ell = cnt + 50048;
    u16* xa  = (u16*)(ell + (size_t)N_NODES * ELLCAP);
    u16* h   = xa + (size_t)N_NODES * 256;
    u16* t   = h  + (size_t)N_NODES * 256;
    u16* W1t = t  + (size_t)N_NODES * 64;
    u16* W2t = W1t + 65536;

    hipMemsetAsync(cnt, 0, 50048 * sizeof(int), stream);

    // one dispatch: ELL fill (2 edges/thread) + bf16 converts
    prep_fill_kernel<<<FILL_B + CVTX_B + CVTW_B, 256, 0, stream>>>(
        x, ei, W1r, W1n, W2n, W2r, xa, cnt, ell, W1t, W2t);

    // layer 1 (separate gather: needs full-occupancy TLP — R11 post-mortem)
    gather1_kernel<<<(N_NODES * 64 + 255) / 256, 256, 0, stream>>>(cnt, ell, xa);
    gemm1_mfma<<<(N_NODES + 127) / 128, 256, 0, stream>>>(xa, W1t, b1, h);

    // layer 2
    gemm2_mfma<<<(N_NODES + 127) / 128, 256, 0, stream>>>(h, W2t, b2, t, out);
    gather2_kernel<<<(N_NODES * 32 + 255) / 256, 256, 0, stream>>>(cnt, ell, t, out);
}

// Round 14
// 227.444 us; speedup vs baseline: 1.0545x; 1.0545x over previous
//
#include <hip/hip_runtime.h>

#define N_NODES 50000
#define N_EDGES 800000
#define NFEAT   128
#define NHID    256
#define NCLASS  64

#define NPASS 8
#define PASS_W ((N_NODES + NPASS - 1) / NPASS)   // 6250 nodes per dst-range pass
#define ELLCAP 64

#define NPAIR   (N_EDGES / 2)                    // 400000 edge pairs
#define ECHUNK2 ((NPAIR + 255) / 256)            // 1563 pair chunks
#define FILL_B  (ECHUNK2 * NPASS)                // 12504
#define CVTX_B  ((N_NODES * 32 + 255) / 256)     // 6250
#define CVTW_B  (((65536 + 32768) + 255) / 256)  // 384

typedef unsigned short u16;
typedef unsigned int   u32;
typedef __attribute__((ext_vector_type(8))) u16   u16x8;
typedef __attribute__((ext_vector_type(8))) short s16x8;
typedef __attribute__((ext_vector_type(4))) float f32x4;

__device__ inline u16 f2bf(float f) {
    u32 u = __float_as_uint(f);
    u32 r = (u + 0x7FFFu + ((u >> 16) & 1u)) >> 16;   // RNE
    return (u16)r;
}
__device__ inline float bflo(u32 v) { return __uint_as_float(v << 16); }
__device__ inline float bfhi(u32 v) { return __uint_as_float(v & 0xFFFF0000u); }

// async global->LDS, 16B per lane; LDS dest must be wave-uniform base + lane*16
#define GLOAD_LDS16(g, l)                                                        \
    __builtin_amdgcn_global_load_lds(                                            \
        (const __attribute__((address_space(1))) u32*)(const void*)(g),          \
        (__attribute__((address_space(3))) u32*)(void*)(l), 16, 0, 0)

// ---------------- fused prep: ELL fill (XCD-binned, 2 edges/thread, u16 slots) | cvt_x | cvt_w ----------------
__global__ __launch_bounds__(256) void prep_fill_kernel(const float* __restrict__ x,
                                                        const int* __restrict__ ei,
                                                        const float* __restrict__ W1r,
                                                        const float* __restrict__ W1n,
                                                        const float* __restrict__ W2n,
                                                        const float* __restrict__ W2r,
                                                        u16* __restrict__ xa,
                                                        int* __restrict__ cnt,
                                                        u16* __restrict__ ell,
                                                        u16* __restrict__ W1t,
                                                        u16* __restrict__ W2t) {
    int b = blockIdx.x;
    if (b < FILL_B) {
        // blockIdx&7 == XCD under round-robin mapping (fill blocks grid-contiguous from 0)
        int p = b & (NPASS - 1);
        int i = (b >> 3) * 256 + threadIdx.x;     // pair index
        if (i >= NPAIR) return;
        int2 d2 = reinterpret_cast<const int2*>(ei + N_EDGES)[i];
        u32 lo = (u32)(p * PASS_W);
        bool in0 = ((u32)d2.x - lo) < (u32)PASS_W;
        bool in1 = ((u32)d2.y - lo) < (u32)PASS_W;
        if (in0 | in1) {
            int2 s2 = reinterpret_cast<const int2*>(ei)[i];
            if (in0) {
                int pos = atomicAdd(&cnt[d2.x], 1);
                if (pos < ELLCAP) ell[(size_t)d2.x * ELLCAP + pos] = (u16)s2.x;
            }
            if (in1) {
                int pos = atomicAdd(&cnt[d2.y], 1);
                if (pos < ELLCAP) ell[(size_t)d2.y * ELLCAP + pos] = (u16)s2.y;
            }
        }
    } else if (b < FILL_B + CVTX_B) {
        int idx = (b - FILL_B) * 256 + threadIdx.x;
        if (idx >= N_NODES * 32) return;
        int r  = idx >> 5;
        int c4 = (idx & 31) * 4;
        float4 v = *reinterpret_cast<const float4*>(x + (size_t)r * NFEAT + c4);
        uint2 o;
        o.x = (u32)f2bf(v.x) | ((u32)f2bf(v.y) << 16);
        o.y = (u32)f2bf(v.z) | ((u32)f2bf(v.w) << 16);
        *reinterpret_cast<uint2*>(xa + (size_t)r * 256 + c4) = o;   // cols 0..127 of combined row
    } else {
        int id = (b - FILL_B - CVTX_B) * 256 + threadIdx.x;
        if (id < 65536) {
            int k = id & 255, n = id >> 8;
            float v = (k < NFEAT) ? W1r[(size_t)k * NHID + n]
                                  : W1n[(size_t)(k - NFEAT) * NHID + n];
            W1t[(size_t)n * 256 + k] = f2bf(v);
        } else if (id < 65536 + 32768) {
            int j = id - 65536;
            int k = j & 255, n = j >> 8;
            float v = (n < NCLASS) ? W2n[(size_t)k * NCLASS + n]
                                   : W2r[(size_t)k * NCLASS + (n - NCLASS)];
            W2t[(size_t)n * 256 + k] = f2bf(v);
        }
    }
}

// ---------------- gather 1: xa[n][128:256] = mean of xa[s][0:128] ----------------
// one wave per node, lane = u32 feature pair; 16-deep neighbor unroll (4KB in flight).
__global__ __launch_bounds__(256) void gather1_kernel(const int* __restrict__ cnt,
                                                      const u16* __restrict__ ell,
                                                      u16* __restrict__ xa) {
    int gtid = blockIdx.x * 256 + threadIdx.x;
    int node = gtid >> 6;
    if (node >= N_NODES) return;
    int lane = threadIdx.x & 63;
    const u32* xrow = reinterpret_cast<const u32*>(xa);   // row stride 128 u32
    const u16* idx = ell + (size_t)node * ELLCAP;
    int deg = cnt[node];
    if (deg > ELLCAP) deg = ELLCAP;
    float ax = 0.0f, ay = 0.0f;
    int j = 0;
    for (; j + 16 <= deg; j += 16) {
        int s[16]; u32 v[16];
        #pragma unroll
        for (int q = 0; q < 16; ++q) s[q] = idx[j + q];
        #pragma unroll
        for (int q = 0; q < 16; ++q) v[q] = xrow[(size_t)s[q] * 128 + lane];
        #pragma unroll
        for (int q = 0; q < 16; ++q) { ax += bflo(v[q]); ay += bfhi(v[q]); }
    }
    for (; j + 8 <= deg; j += 8) {
        int s[8]; u32 v[8];
        #pragma unroll
        for (int q = 0; q < 8; ++q) s[q] = idx[j + q];
        #pragma unroll
        for (int q = 0; q < 8; ++q) v[q] = xrow[(size_t)s[q] * 128 + lane];
        #pragma unroll
        for (int q = 0; q < 8; ++q) { ax += bflo(v[q]); ay += bfhi(v[q]); }
    }
    for (; j < deg; ++j) {
        u32 v = xrow[(size_t)idx[j] * 128 + lane];
        ax += bflo(v);
        ay += bfhi(v);
    }
    float invd = 1.0f / fmaxf((float)deg, 1.0f);
    u32 packed = (u32)f2bf(ax * invd) | ((u32)f2bf(ay * invd) << 16);
    reinterpret_cast<u32*>(xa + (size_t)node * 256 + 128)[lane] = packed;
}

// ---------------- gather 2: out[n][:] += mean of t[s][:] ----------------
// 2 nodes per wave (t rows = 32 u32), lane&31 = u32 pair; 16-deep unroll.
__global__ __launch_bounds__(256) void gather2_kernel(const int* __restrict__ cnt,
                                                      const u16* __restrict__ ell,
                                                      const u16* __restrict__ t,
                                                      float* __restrict__ out) {
    int gtid = blockIdx.x * 256 + threadIdx.x;
    int wave = gtid >> 6;
    int lane = threadIdx.x & 63;
    int node = wave * 2 + (lane >> 5);
    int l    = lane & 31;
    if (node >= N_NODES) return;
    const u32* trow = reinterpret_cast<const u32*>(t);    // row stride 32 u32
    const u16* idx = ell + (size_t)node * ELLCAP;
    int deg = cnt[node];
    if (deg > ELLCAP) deg = ELLCAP;
    float ax = 0.0f, ay = 0.0f;
    int j = 0;
    for (; j + 16 <= deg; j += 16) {
        int s[16]; u32 v[16];
        #pragma unroll
        for (int q = 0; q < 16; ++q) s[q] = idx[j + q];
        #pragma unroll
        for (int q = 0; q < 16; ++q) v[q] = trow[(size_t)s[q] * 32 + l];
        #pragma unroll
        for (int q = 0; q < 16; ++q) { ax += bflo(v[q]); ay += bfhi(v[q]); }
    }
    for (; j + 8 <= deg; j += 8) {
        int s[8]; u32 v[8];
        #pragma unroll
        for (int q = 0; q < 8; ++q) s[q] = idx[j + q];
        #pragma unroll
        for (int q = 0; q < 8; ++q) v[q] = trow[(size_t)s[q] * 32 + l];
        #pragma unroll
        for (int q = 0; q < 8; ++q) { ax += bflo(v[q]); ay += bfhi(v[q]); }
    }
    for (; j < deg; ++j) {
        u32 v = trow[(size_t)idx[j] * 32 + l];
        ax += bflo(v); ay += bfhi(v);
    }
    float invd = 1.0f / fmaxf((float)deg, 1.0f);
    float* o = out + (size_t)node * NCLASS + l * 2;
    o[0] += ax * invd;
    o[1] += ay * invd;
}

// ---------------- MFMA GEMM 1: h = relu(xa @ W1t^T + b1), bf16 out ----------------
// R12-proven shape: BM=128, BN=128 (dim3 grid), LDS 16 KB, acc[4][4].
// R13's BN=256 single-grid variant regressed (-10 us): fewer blocks + 128 VGPR acc.
__global__ __launch_bounds__(256) void gemm1_mfma(const u16* __restrict__ xa,
                                                  const u16* __restrict__ W1t,
                                                  const float* __restrict__ b1,
                                                  u16* __restrict__ h) {
    __shared__ u16 As[128 * 32];
    __shared__ u16 Bs[128 * 32];
    const int tid = threadIdx.x;
    const int r0 = blockIdx.x * 128;
    const int n0 = blockIdx.y * 128;
    const int wid = tid >> 6, ln = tid & 63;
    const int wm = (wid & 1) * 64, wn = (wid >> 1) * 64;
    const int lr = ln & 15;
    const int lq = ln >> 4;

    f32x4 acc[4][4] = {};

    for (int k0 = 0; k0 < 256; k0 += 32) {
        #pragma unroll
        for (int it = 0; it < 2; ++it) {
            int c   = it * 256 + tid;      // chunk 0..511; LDS dest = c*16 B (lane-contiguous)
            int row = c >> 2;
            int ko  = (c & 3) * 8;
            GLOAD_LDS16(xa  + (size_t)(r0 + row) * 256 + k0 + ko, As + c * 8);
            GLOAD_LDS16(W1t + (size_t)(n0 + row) * 256 + k0 + ko, Bs + c * 8);
        }
        __syncthreads();

        s16x8 af[4], bf[4];
        #pragma unroll
        for (int i = 0; i < 4; ++i)
            af[i] = *reinterpret_cast<const s16x8*>(As + (wm + i * 16 + lr) * 32 + lq * 8);
        #pragma unroll
        for (int j = 0; j < 4; ++j)
            bf[j] = *reinterpret_cast<const s16x8*>(Bs + (wn + j * 16 + lr) * 32 + lq * 8);
        #pragma unroll
        for (int i = 0; i < 4; ++i)
            #pragma unroll
            for (int j = 0; j < 4; ++j)
                acc[i][j] = __builtin_amdgcn_mfma_f32_16x16x32_bf16(af[i], bf[j], acc[i][j], 0, 0, 0);
        __syncthreads();
    }

    #pragma unroll
    for (int i = 0; i < 4; ++i) {
        #pragma unroll
        for (int j = 0; j < 4; ++j) {
            int col = n0 + wn + j * 16 + lr;
            float bias = b1[col];
            #pragma unroll
            for (int r = 0; r < 4; ++r) {
                int row = r0 + wm + i * 16 + lq * 4 + r;
                if (row < N_NODES)
                    h[(size_t)row * 256 + col] = f2bf(fmaxf(acc[i][j][r] + bias, 0.0f));
            }
        }
    }
}

// ---------------- MFMA GEMM 2 (fused): cols 0..63 -> t (bf16), 64..127 -> out+b2 (f32) ----------------
__global__ __launch_bounds__(256) void gemm2_mfma(const u16* __restrict__ h,
                                                  const u16* __restrict__ W2t,
                                                  const float* __restrict__ b2,
                                                  u16* __restrict__ t,
                                                  float* __restrict__ out) {
    __shared__ u16 As[128 * 32];
    __shared__ u16 Bs[128 * 32];
    const int tid = threadIdx.x;
    const int r0 = blockIdx.x * 128;
    const int wid = tid >> 6, ln = tid & 63;
    const int wm = (wid & 1) * 64, wn = (wid >> 1) * 64;
    const int lr = ln & 15;
    const int lq = ln >> 4;

    f32x4 acc[4][4] = {};

    for (int k0 = 0; k0 < 256; k0 += 32) {
        #pragma unroll
        for (int it = 0; it < 2; ++it) {
            int c   = it * 256 + tid;
            int row = c >> 2;
            int ko  = (c & 3) * 8;
            GLOAD_LDS16(h   + (size_t)(r0 + row) * 256 + k0 + ko, As + c * 8);
            GLOAD_LDS16(W2t + (size_t)row * 256 + k0 + ko,        Bs + c * 8);
        }
        __syncthreads();

        s16x8 af[4], bf[4];
        #pragma unroll
        for (int i = 0; i < 4; ++i)
            af[i] = *reinterpret_cast<const s16x8*>(As + (wm + i * 16 + lr) * 32 + lq * 8);
        #pragma unroll
        for (int j = 0; j < 4; ++j)
            bf[j] = *reinterpret_cast<const s16x8*>(Bs + (wn + j * 16 + lr) * 32 + lq * 8);
        #pragma unroll
        for (int i = 0; i < 4; ++i)
            #pragma unroll
            for (int j = 0; j < 4; ++j)
                acc[i][j] = __builtin_amdgcn_mfma_f32_16x16x32_bf16(af[i], bf[j], acc[i][j], 0, 0, 0);
        __syncthreads();
    }

    #pragma unroll
    for (int i = 0; i < 4; ++i) {
        #pragma unroll
        for (int j = 0; j < 4; ++j) {
            int col = wn + j * 16 + lr;   // 0..127
            #pragma unroll
            for (int r = 0; r < 4; ++r) {
                int row = r0 + wm + i * 16 + lq * 4 + r;
                if (row >= N_NODES) continue;
                if (col < NCLASS) {
                    t[(size_t)row * NCLASS + col] = f2bf(acc[i][j][r]);
                } else {
                    int c = col - NCLASS;
                    out[(size_t)row * NCLASS + c] = acc[i][j][r] + b2[c];
                }
            }
        }
    }
}

extern "C" void kernel_launch(void* const* d_in, const int* in_sizes, int n_in,
                              void* d_out, int out_size, void* d_ws, size_t ws_size,
                              hipStream_t stream) {
    const float* x    = (const float*)d_in[0];
    const int*   ei   = (const int*)d_in[1];
    const float* W1n  = (const float*)d_in[2];
    const float* W1r  = (const float*)d_in[3];
    const float* b1   = (const float*)d_in[4];
    const float* W2n  = (const float*)d_in[5];
    const float* W2r  = (const float*)d_in[6];
    const float* b2   = (const float*)d_in[7];
    float* out = (float*)d_out;

    // workspace: cnt[50048] | ell u16[50000*64] | xa[50000*256] | h[50000*256] | t[50000*64] | W1t | W2t
    int* cnt = (int*)d_ws;
    u16* ell = (u16*)(cnt + 50048);
    u16* xa  = ell + (size_t)N_NODES * ELLCAP;
    u16* h   = xa + (size_t)N_NODES * 256;
    u16* t   = h  + (size_t)N_NODES * 256;
    u16* W1t = t  + (size_t)N_NODES * 64;
    u16* W2t = W1t + 65536;

    hipMemsetAsync(cnt, 0, 50048 * sizeof(int), stream);

    // one dispatch: ELL fill (2 edges/thread) + bf16 converts
    prep_fill_kernel<<<FILL_B + CVTX_B + CVTW_B, 256, 0, stream>>>(
        x, ei, W1r, W1n, W2n, W2r, xa, cnt, ell, W1t, W2t);

    // layer 1 (separate gather: needs full-occupancy TLP — R11 post-mortem)
    gather1_kernel<<<(N_NODES * 64 + 255) / 256, 256, 0, stream>>>(cnt, ell, xa);
    gemm1_mfma<<<dim3((N_NODES + 127) / 128, 2), 256, 0, stream>>>(xa, W1t, b1, h);

    // layer 2
    gemm2_mfma<<<(N_NODES + 127) / 128, 256, 0, stream>>>(h, W2t, b2, t, out);
    gather2_kernel<<<(N_NODES * 32 + 255) / 256, 256, 0, stream>>>(cnt, ell, t, out);
}